// Round 1
// baseline (1209.361 us; speedup 1.0000x reference)
//
#include <hip/hip_runtime.h>
#include <math.h>

// Problem constants (from reference)
#define D 128
#define H 4
#define DH 32
#define L 8
#define GPITCH 132   // LDS pitch for A-tile (conflict-aware, 16B-aligned rows)

// ---------------------------------------------------------------------------
// Fold weights:
//  which 0: wkaT[c][k] = sum_d Wk1[k, h*32+d] * Watt1[h,d,f]   (c = h*32+f)
//  which 1: wvmT[c][k] = sum_d Wv1[k, h*32+d] * Wmsg1[h,d,f]
//  which 2: wqT [c][k] = Wq0[k, c]
//  which 3: w1T [c][k] = sum_d Wout0[k,d] * lin_w[d,c]
//  which 4: lwT [c][k] = lin_w[k, c]
// All stored transposed (col-major) so the GEMM reads W^T rows contiguously.
// ---------------------------------------------------------------------------
__global__ __launch_bounds__(256) void fold_weights(
    const float* __restrict__ Wk1, const float* __restrict__ Wq0,
    const float* __restrict__ Wv1, const float* __restrict__ Watt1,
    const float* __restrict__ Wmsg1, const float* __restrict__ Wout0,
    const float* __restrict__ lin_w,
    float* __restrict__ wkaT, float* __restrict__ wvmT,
    float* __restrict__ wqT, float* __restrict__ w1T, float* __restrict__ lwT)
{
    int id = blockIdx.x * 256 + threadIdx.x;   // < 5*16384
    int which = id >> 14;
    int idx = id & 16383;
    int col = idx & 127;
    int k = idx >> 7;
    if (which == 0) {
        int h = col >> 5, f = col & 31;
        float s = 0.f;
        for (int d = 0; d < 32; ++d)
            s += Wk1[k * 128 + h * 32 + d] * Watt1[h * 1024 + d * 32 + f];
        wkaT[col * 128 + k] = s;
    } else if (which == 1) {
        int h = col >> 5, f = col & 31;
        float s = 0.f;
        for (int d = 0; d < 32; ++d)
            s += Wv1[k * 128 + h * 32 + d] * Wmsg1[h * 1024 + d * 32 + f];
        wvmT[col * 128 + k] = s;
    } else if (which == 2) {
        wqT[col * 128 + k] = Wq0[k * 128 + col];
    } else if (which == 3) {
        float s = 0.f;
        for (int d = 0; d < 128; ++d)
            s += Wout0[k * 128 + d] * lin_w[d * 128 + col];
        w1T[col * 128 + k] = s;
    } else {
        lwT[col * 128 + k] = lin_w[k * 128 + col];
    }
}

// ---------------------------------------------------------------------------
// Node encoder: embedding lookup, pad-masked mean pool, relu.
// Thread per (node, d). Lanes cover d -> coalesced 512B per token row.
// ---------------------------------------------------------------------------
__global__ __launch_bounds__(256) void encode_nodes(
    const int* __restrict__ tok, const float* __restrict__ emb,
    float* __restrict__ x, int N)
{
    int i = blockIdx.x * 256 + threadIdx.x;
    if (i >= N * 128) return;
    int n = i >> 7, d = i & 127;
    float acc = 0.f;
    int cnt = 0;
#pragma unroll
    for (int l = 0; l < L; ++l) {
        int t = tok[n * L + l];
        if (t != 0) { cnt++; acc += emb[t * 128 + d]; }
    }
    float dn = fmaxf((float)cnt, 1.0f);
    x[i] = fmaxf(acc / dn, 0.f);
}

// ---------------------------------------------------------------------------
// Register-tiled fp32 GEMM: Y[N,128] = f(A0)[N,128] @ W0 (+ A1 @ W1) (+ bias)
// WT* are the 128x128 weights stored TRANSPOSED (WT[c*128+k] = W[k][c]).
// Block: 128 rows x 128 cols, 256 threads (16x16), 8x8 per thread
// (interleaved row/col assignment r = ty+16i, c = tx+16j for bank spread).
// f = tanh-gelu when gelu0 != 0 (applied to A0 during staging).
// ---------------------------------------------------------------------------
__global__ __launch_bounds__(256) void gemm_rt(
    const float* __restrict__ A0, const float* __restrict__ WT0,
    const float* __restrict__ A1, const float* __restrict__ WT1,
    const float* __restrict__ bias, float* __restrict__ Y,
    int N, int gelu0)
{
    __shared__ float sa[128 * GPITCH];
    int tid = threadIdx.x;
    int tx = tid & 15, ty = tid >> 4;
    int rbase = blockIdx.x * 128;

    float acc[8][8];
#pragma unroll
    for (int i = 0; i < 8; ++i)
#pragma unroll
        for (int j = 0; j < 8; ++j) acc[i][j] = 0.f;

    for (int pass = 0; pass < 2; ++pass) {
        const float* A  = pass ? A1  : A0;
        const float* WT = pass ? WT1 : WT0;
        if (A == nullptr) break;
        if (pass) __syncthreads();
        // stage A tile (coalesced global read, conflict-free LDS write)
        for (int idx = tid; idx < 128 * 128; idx += 256) {
            int r = idx >> 7, k = idx & 127;
            int row = rbase + r;
            float v = (row < N) ? A[(size_t)row * 128 + k] : 0.f;
            if (gelu0 && pass == 0) {
                float xv = v;
                v = 0.5f * xv * (1.0f + tanhf(0.7978845608028654f * (xv + 0.044715f * xv * xv * xv)));
            }
            sa[r * GPITCH + k] = v;
        }
        __syncthreads();

        for (int k0 = 0; k0 < 128; k0 += 4) {
            float xf[8][4];
#pragma unroll
            for (int i = 0; i < 8; ++i) {
                float4 t = *(const float4*)&sa[(ty + 16 * i) * GPITCH + k0];
                xf[i][0] = t.x; xf[i][1] = t.y; xf[i][2] = t.z; xf[i][3] = t.w;
            }
            float wf[8][4];
#pragma unroll
            for (int j = 0; j < 8; ++j) {
                float4 t = *(const float4*)&WT[(size_t)(tx + 16 * j) * 128 + k0];
                wf[j][0] = t.x; wf[j][1] = t.y; wf[j][2] = t.z; wf[j][3] = t.w;
            }
#pragma unroll
            for (int kk = 0; kk < 4; ++kk)
#pragma unroll
                for (int i = 0; i < 8; ++i)
#pragma unroll
                    for (int j = 0; j < 8; ++j)
                        acc[i][j] += xf[i][kk] * wf[j][kk];
        }
    }

#pragma unroll
    for (int i = 0; i < 8; ++i) {
        int row = rbase + ty + 16 * i;
        if (row < N) {
#pragma unroll
            for (int j = 0; j < 8; ++j) {
                int c = tx + 16 * j;
                float v = acc[i][j];
                if (bias) v += bias[c];
                Y[(size_t)row * 128 + c] = v;
            }
        }
    }
}

// ---------------------------------------------------------------------------
// Edge pass A: per-edge per-head score = (kt[src,h,:] . qa[dst,h,:]) * mu[h]/sqrt(32)
// e = exp(score) (max-shift skipped: scores ~1e-4, softmax is shift-invariant,
// epsilon perturbation ~1e-13). Store e, atomic-add denominator per (dst,h).
// 2 edges per 256-thread block; 128 lanes per edge (lane = h*32+f). Coalesced.
// ---------------------------------------------------------------------------
__global__ __launch_bounds__(256) void edge_score(
    const float* __restrict__ kt, const float* __restrict__ qa,
    const int* __restrict__ src_idx, const int* __restrict__ dst_idx,
    const float* __restrict__ mu1, float* __restrict__ ealpha,
    float* __restrict__ denom, int E)
{
    int e = blockIdx.x * 2 + (threadIdx.x >> 7);
    if (e >= E) return;
    int lane = threadIdx.x & 127;
    int h = lane >> 5;
    int src = src_idx[e], dst = dst_idx[e];
    float p = kt[(size_t)src * 128 + lane] * qa[(size_t)dst * 128 + lane];
    p += __shfl_down(p, 16, 32);
    p += __shfl_down(p, 8, 32);
    p += __shfl_down(p, 4, 32);
    p += __shfl_down(p, 2, 32);
    p += __shfl_down(p, 1, 32);
    if ((lane & 31) == 0) {
        float sc = p * mu1[h] * 0.17677669529663689f;  // 1/sqrt(32)
        float ev = expf(sc);
        ealpha[(size_t)e * 4 + h] = ev;
        unsafeAtomicAdd(&denom[(size_t)dst * 4 + h], ev);
    }
}

// ---------------------------------------------------------------------------
// Edge pass C: agg[dst, :] += alpha * mt[src, :]  (alpha per head)
// ---------------------------------------------------------------------------
__global__ __launch_bounds__(256) void edge_agg(
    const float* __restrict__ mt, const int* __restrict__ src_idx,
    const int* __restrict__ dst_idx, const float* __restrict__ ealpha,
    const float* __restrict__ denom, float* __restrict__ agg, int E)
{
    int e = blockIdx.x * 2 + (threadIdx.x >> 7);
    if (e >= E) return;
    int lane = threadIdx.x & 127;
    int h = lane >> 5;
    int src = src_idx[e], dst = dst_idx[e];
    float alpha = ealpha[(size_t)e * 4 + h] / (denom[(size_t)dst * 4 + h] + 1e-9f);
    unsafeAtomicAdd(&agg[(size_t)dst * 128 + lane], alpha * mt[(size_t)src * 128 + lane]);
}

// ---------------------------------------------------------------------------
extern "C" void kernel_launch(void* const* d_in, const int* in_sizes, int n_in,
                              void* d_out, int out_size, void* d_ws, size_t ws_size,
                              hipStream_t stream)
{
    const int*   tok_a  = (const int*)d_in[0];
    const int*   tok_p  = (const int*)d_in[1];
    const int*   edge_pa = (const int*)d_in[3];
    const float* emb    = (const float*)d_in[4];
    const float* Wk     = (const float*)d_in[5];
    const float* Wq     = (const float*)d_in[6];
    const float* Wv     = (const float*)d_in[7];
    const float* Watt   = (const float*)d_in[8];
    const float* Wmsg   = (const float*)d_in[9];
    const float* mu     = (const float*)d_in[10];
    const float* Wout   = (const float*)d_in[11];
    const float* lin_w  = (const float*)d_in[12];
    const float* lin_b  = (const float*)d_in[13];

    int Na = in_sizes[0] / L;
    int Np = in_sizes[1] / L;
    int E  = in_sizes[3] / 2;
    float* out = (float*)d_out;

    // workspace layout (floats)
    float* ws = (float*)d_ws;
    size_t off = 0;
    float* xa     = ws + off; off += (size_t)Na * 128;
    float* xp     = ws + off; off += (size_t)Np * 128;   // reused as agg later
    float* qa     = ws + off; off += (size_t)Na * 128;
    float* kt     = ws + off; off += (size_t)Np * 128;
    float* mt     = ws + off; off += (size_t)Np * 128;
    float* ealpha = ws + off; off += (size_t)E * 4;
    float* denom  = ws + off; off += (size_t)Na * 4;
    float* wkaT   = ws + off; off += 16384;
    float* wvmT   = ws + off; off += 16384;
    float* wqT    = ws + off; off += 16384;
    float* w1T    = ws + off; off += 16384;
    float* lwT    = ws + off; off += 16384;
    float* agg    = xp;  // xp fully consumed (kt, mt) before agg is written

    // 1) fold weights (tiny)
    fold_weights<<<(5 * 16384) / 256, 256, 0, stream>>>(
        Wk + 16384, Wq, Wv + 16384, Watt + 4096, Wmsg + 4096, Wout, lin_w,
        wkaT, wvmT, wqT, w1T, lwT);

    // 2) node encoding
    encode_nodes<<<(Na * 128 + 255) / 256, 256, 0, stream>>>(tok_a, emb, xa, Na);
    encode_nodes<<<(Np * 128 + 255) / 256, 256, 0, stream>>>(tok_p, emb, xp, Np);

    // 3) projections: qa = xa@Wq0, kt = xp@(Wk1*Watt1), mt = xp@(Wv1*Wmsg1)
    int gba = (Na + 127) / 128;
    int gbp = (Np + 127) / 128;
    gemm_rt<<<gba, 256, 0, stream>>>(xa, wqT, nullptr, nullptr, nullptr, qa, Na, 0);
    gemm_rt<<<gbp, 256, 0, stream>>>(xp, wkaT, nullptr, nullptr, nullptr, kt, Np, 0);
    gemm_rt<<<gbp, 256, 0, stream>>>(xp, wvmT, nullptr, nullptr, nullptr, mt, Np, 0);

    // 4) zero accumulators (xp no longer needed -> reuse as agg)
    hipMemsetAsync(agg, 0, (size_t)Na * 128 * sizeof(float), stream);
    hipMemsetAsync(denom, 0, (size_t)Na * 4 * sizeof(float), stream);

    // 5) edge passes
    int eb = (E + 1) / 2;
    edge_score<<<eb, 256, 0, stream>>>(kt, qa, edge_pa, edge_pa + E, mu + 4,
                                       ealpha, denom, E);
    edge_agg<<<eb, 256, 0, stream>>>(mt, edge_pa, edge_pa + E, ealpha, denom, agg, E);

    // 6) output head: out = gelu(agg)@(Wout0@lin_w) + xa@lin_w + lin_b
    gemm_rt<<<gba, 256, 0, stream>>>(agg, w1T, xa, lwT, lin_b, out, Na, 1);
}

// Round 2
// 765.900 us; speedup vs baseline: 1.5790x; 1.5790x over previous
//
#include <hip/hip_runtime.h>
#include <math.h>

// Problem constants (from reference)
#define D 128
#define H 4
#define DH 32
#define L 8
#define GPITCH 132   // LDS pitch for A-tile (conflict-aware, 16B-aligned rows)

typedef unsigned int  u32;
typedef unsigned short u16;

// fp32 -> bf16 round-to-nearest-even (values are well-behaved, no NaN path)
__device__ inline u16 f2bf(float x) {
    u32 u = __float_as_uint(x);
    return (u16)((u + 0x7fffu + ((u >> 16) & 1u)) >> 16);
}
// unpack 2 packed bf16 (low = even elem, high = odd elem)
__device__ inline float2 bf2f2(u32 v) {
    float2 r;
    r.x = __uint_as_float(v << 16);
    r.y = __uint_as_float(v & 0xffff0000u);
    return r;
}

// ---------------------------------------------------------------------------
// Fold weights:
//  which 0: wkaT[c][k] = sum_d Wk1[k, h*32+d] * Watt1[h,d,f]   (c = h*32+f)
//  which 1: wvmT[c][k] = sum_d Wv1[k, h*32+d] * Wmsg1[h,d,f]
//  which 2: wqT [c][k] = Wq0[k, c]
//  which 3: w1T [c][k] = sum_d Wout0[k,d] * lin_w[d,c]
//  which 4: lwT [c][k] = lin_w[k, c]
// ---------------------------------------------------------------------------
__global__ __launch_bounds__(256) void fold_weights(
    const float* __restrict__ Wk1, const float* __restrict__ Wq0,
    const float* __restrict__ Wv1, const float* __restrict__ Watt1,
    const float* __restrict__ Wmsg1, const float* __restrict__ Wout0,
    const float* __restrict__ lin_w,
    float* __restrict__ wkaT, float* __restrict__ wvmT,
    float* __restrict__ wqT, float* __restrict__ w1T, float* __restrict__ lwT)
{
    int id = blockIdx.x * 256 + threadIdx.x;   // < 5*16384
    int which = id >> 14;
    int idx = id & 16383;
    int col = idx & 127;
    int k = idx >> 7;
    if (which == 0) {
        int h = col >> 5, f = col & 31;
        float s = 0.f;
        for (int d = 0; d < 32; ++d)
            s += Wk1[k * 128 + h * 32 + d] * Watt1[h * 1024 + d * 32 + f];
        wkaT[col * 128 + k] = s;
    } else if (which == 1) {
        int h = col >> 5, f = col & 31;
        float s = 0.f;
        for (int d = 0; d < 32; ++d)
            s += Wv1[k * 128 + h * 32 + d] * Wmsg1[h * 1024 + d * 32 + f];
        wvmT[col * 128 + k] = s;
    } else if (which == 2) {
        wqT[col * 128 + k] = Wq0[k * 128 + col];
    } else if (which == 3) {
        float s = 0.f;
        for (int d = 0; d < 128; ++d)
            s += Wout0[k * 128 + d] * lin_w[d * 128 + col];
        w1T[col * 128 + k] = s;
    } else {
        lwT[col * 128 + k] = lin_w[k * 128 + col];
    }
}

// ---------------------------------------------------------------------------
// Node encoder: embedding lookup, pad-masked mean pool, relu. f32 out.
// ---------------------------------------------------------------------------
__global__ __launch_bounds__(256) void encode_nodes(
    const int* __restrict__ tok, const float* __restrict__ emb,
    float* __restrict__ x, int N)
{
    int i = blockIdx.x * 256 + threadIdx.x;
    if (i >= N * 128) return;
    int n = i >> 7, d = i & 127;
    float acc = 0.f;
    int cnt = 0;
#pragma unroll
    for (int l = 0; l < L; ++l) {
        int t = tok[n * L + l];
        if (t != 0) { cnt++; acc += emb[t * 128 + d]; }
    }
    float dn = fmaxf((float)cnt, 1.0f);
    x[i] = fmaxf(acc / dn, 0.f);
}

// ---------------------------------------------------------------------------
// Register-tiled fp32 GEMM: Y[N,128] = f(A0)[N,128] @ W0 (+ A1 @ W1) (+ bias)
// WT* stored transposed (WT[c*128+k] = W[k][c]).
// aggmode: A0 is bf16 agg; per-element divide by (denom[row,h]+1e-9), gelu.
// outbf:   store Y as bf16.
// ---------------------------------------------------------------------------
__global__ __launch_bounds__(256) void gemm_rt(
    const void* __restrict__ A0v, const float* __restrict__ WT0,
    const float* __restrict__ A1, const float* __restrict__ WT1,
    const float* __restrict__ bias, const float* __restrict__ denom,
    void* __restrict__ Yv, int N, int aggmode, int outbf)
{
    __shared__ float sa[128 * GPITCH];
    int tid = threadIdx.x;
    int tx = tid & 15, ty = tid >> 4;
    int rbase = blockIdx.x * 128;

    float acc[8][8];
#pragma unroll
    for (int i = 0; i < 8; ++i)
#pragma unroll
        for (int j = 0; j < 8; ++j) acc[i][j] = 0.f;

    for (int pass = 0; pass < 2; ++pass) {
        if (pass == 1 && A1 == nullptr) break;
        const float* WT = pass ? WT1 : WT0;
        if (pass) __syncthreads();
        for (int idx = tid; idx < 128 * 128; idx += 256) {
            int r = idx >> 7, k = idx & 127;
            int row = rbase + r;
            float v = 0.f;
            if (row < N) {
                if (pass == 1) {
                    v = A1[(size_t)row * 128 + k];
                } else if (aggmode) {
                    u16 uv = ((const u16*)A0v)[(size_t)row * 128 + k];
                    float av = __uint_as_float(((u32)uv) << 16);
                    av /= (denom[(size_t)row * 4 + (k >> 5)] + 1e-9f);
                    v = 0.5f * av * (1.0f + tanhf(0.7978845608028654f *
                        (av + 0.044715f * av * av * av)));
                } else {
                    v = ((const float*)A0v)[(size_t)row * 128 + k];
                }
            }
            sa[r * GPITCH + k] = v;
        }
        __syncthreads();

        for (int k0 = 0; k0 < 128; k0 += 4) {
            float xf[8][4];
#pragma unroll
            for (int i = 0; i < 8; ++i) {
                float4 t = *(const float4*)&sa[(ty + 16 * i) * GPITCH + k0];
                xf[i][0] = t.x; xf[i][1] = t.y; xf[i][2] = t.z; xf[i][3] = t.w;
            }
            float wf[8][4];
#pragma unroll
            for (int j = 0; j < 8; ++j) {
                float4 t = *(const float4*)&WT[(size_t)(tx + 16 * j) * 128 + k0];
                wf[j][0] = t.x; wf[j][1] = t.y; wf[j][2] = t.z; wf[j][3] = t.w;
            }
#pragma unroll
            for (int kk = 0; kk < 4; ++kk)
#pragma unroll
                for (int i = 0; i < 8; ++i)
#pragma unroll
                    for (int j = 0; j < 8; ++j)
                        acc[i][j] += xf[i][kk] * wf[j][kk];
        }
    }

#pragma unroll
    for (int i = 0; i < 8; ++i) {
        int row = rbase + ty + 16 * i;
        if (row < N) {
#pragma unroll
            for (int j = 0; j < 8; ++j) {
                int c = tx + 16 * j;
                float v = acc[i][j];
                if (bias) v += bias[c];
                if (outbf) ((u16*)Yv)[(size_t)row * 128 + c] = f2bf(v);
                else       ((float*)Yv)[(size_t)row * 128 + c] = v;
            }
        }
    }
}

// ---------------------------------------------------------------------------
// Fused edge pass: one wave per edge (4 edges / 256-thread block).
// Each lane covers 2 contiguous bf16 elems (lane -> elems 2l, 2l+1).
// score_h = (kt[src,h,:] . qa[dst,h,:]) * mu[h] / sqrt(32);  ev = exp(score)
// (max-shift skipped: softmax is shift-invariant; scores are tiny)
// denom[dst,h]   += ev                      (f32 atomic, 4/edge)
// agg[dst, :]    += ev * mt[src, :]         (packed bf16 atomics, 64/edge)
// Normalization by denom happens in the final GEMM's staging.
// ---------------------------------------------------------------------------
__global__ __launch_bounds__(256) void edge_fused(
    const u16* __restrict__ kt, const u16* __restrict__ qa,
    const u16* __restrict__ mt,
    const int* __restrict__ src_idx, const int* __restrict__ dst_idx,
    const float* __restrict__ mu1,
    float* __restrict__ denom, u16* __restrict__ agg, int E)
{
    int e = blockIdx.x * 4 + (threadIdx.x >> 6);
    if (e >= E) return;
    int lane = threadIdx.x & 63;
    int src = src_idx[e], dst = dst_idx[e];

    // issue all three gathers up front (independent; hides latency)
    u32 kv = ((const u32*)(kt + (size_t)src * 128))[lane];
    u32 qv = ((const u32*)(qa + (size_t)dst * 128))[lane];
    u32 mv = ((const u32*)(mt + (size_t)src * 128))[lane];

    float2 kf = bf2f2(kv), qf = bf2f2(qv);
    float p = kf.x * qf.x + kf.y * qf.y;
    // head h = lane>>4 (16 lanes = 32 elems per head); xor-reduce within group
    p += __shfl_xor(p, 1, 16);
    p += __shfl_xor(p, 2, 16);
    p += __shfl_xor(p, 4, 16);
    p += __shfl_xor(p, 8, 16);
    int h = lane >> 4;
    float ev = __expf(p * mu1[h] * 0.17677669529663689f);  // 1/sqrt(32)

    if ((lane & 15) == 0)
        unsafeAtomicAdd(&denom[(size_t)dst * 4 + h], ev);

    float2 mf = bf2f2(mv);
    u32 packed = ((u32)f2bf(mf.y * ev) << 16) | (u32)f2bf(mf.x * ev);
    u32* dp = (u32*)(agg + (size_t)dst * 128) + lane;
    asm volatile("global_atomic_pk_add_bf16 %0, %1, off"
                 :: "v"(dp), "v"(packed) : "memory");
}

// ---------------------------------------------------------------------------
extern "C" void kernel_launch(void* const* d_in, const int* in_sizes, int n_in,
                              void* d_out, int out_size, void* d_ws, size_t ws_size,
                              hipStream_t stream)
{
    const int*   tok_a   = (const int*)d_in[0];
    const int*   tok_p   = (const int*)d_in[1];
    const int*   edge_pa = (const int*)d_in[3];
    const float* emb     = (const float*)d_in[4];
    const float* Wk      = (const float*)d_in[5];
    const float* Wq      = (const float*)d_in[6];
    const float* Wv      = (const float*)d_in[7];
    const float* Watt    = (const float*)d_in[8];
    const float* Wmsg    = (const float*)d_in[9];
    const float* mu      = (const float*)d_in[10];
    const float* Wout    = (const float*)d_in[11];
    const float* lin_w   = (const float*)d_in[12];
    const float* lin_b   = (const float*)d_in[13];

    int Na = in_sizes[0] / L;
    int Np = in_sizes[1] / L;
    int E  = in_sizes[3] / 2;
    float* out = (float*)d_out;

    // workspace layout
    float* ws = (float*)d_ws;
    float* xa    = ws;                          // Na*128 f32
    float* xp    = xa + (size_t)Na * 128;       // Np*128 f32
    u16*   qa    = (u16*)(xp + (size_t)Np * 128); // Na*128 bf16
    u16*   kt    = qa + (size_t)Na * 128;       // Np*128 bf16
    u16*   mt    = kt + (size_t)Np * 128;       // Np*128 bf16
    u16*   agg   = mt + (size_t)Np * 128;       // Na*128 bf16
    float* denom = (float*)(agg + (size_t)Na * 128); // Na*4 f32
    float* wkaT  = denom + (size_t)Na * 4;
    float* wvmT  = wkaT + 16384;
    float* wqT   = wvmT + 16384;
    float* w1T   = wqT + 16384;
    float* lwT   = w1T + 16384;

    // 1) fold weights (tiny)
    fold_weights<<<(5 * 16384) / 256, 256, 0, stream>>>(
        Wk + 16384, Wq, Wv + 16384, Watt + 4096, Wmsg + 4096, Wout, lin_w,
        wkaT, wvmT, wqT, w1T, lwT);

    // 2) node encoding
    encode_nodes<<<(Na * 128 + 255) / 256, 256, 0, stream>>>(tok_a, emb, xa, Na);
    encode_nodes<<<(Np * 128 + 255) / 256, 256, 0, stream>>>(tok_p, emb, xp, Np);

    // 3) projections (bf16 outputs): qa = xa@Wq0, kt = xp@(Wk1*Watt1), mt = xp@(Wv1*Wmsg1)
    int gba = (Na + 127) / 128;
    int gbp = (Np + 127) / 128;
    gemm_rt<<<gba, 256, 0, stream>>>(xa, wqT, nullptr, nullptr, nullptr, nullptr, qa, Na, 0, 1);
    gemm_rt<<<gbp, 256, 0, stream>>>(xp, wkaT, nullptr, nullptr, nullptr, nullptr, kt, Np, 0, 1);
    gemm_rt<<<gbp, 256, 0, stream>>>(xp, wvmT, nullptr, nullptr, nullptr, nullptr, mt, Np, 0, 1);

    // 4) zero accumulators
    hipMemsetAsync(agg, 0, (size_t)Na * 128 * sizeof(u16), stream);
    hipMemsetAsync(denom, 0, (size_t)Na * 4 * sizeof(float), stream);

    // 5) fused edge pass (unnormalized aggregate + denominator)
    edge_fused<<<(E + 3) / 4, 256, 0, stream>>>(kt, qa, mt, edge_pa, edge_pa + E,
                                                mu + 4, denom, agg, E);

    // 6) output head: out = gelu(agg/denom)@(Wout0@lin_w) + xa@lin_w + lin_b
    gemm_rt<<<gba, 256, 0, stream>>>(agg, w1T, xa, lwT, lin_b, denom, out, Na, 1, 0);
}